// Round 7
// baseline (210.917 us; speedup 1.0000x reference)
//
#include <hip/hip_runtime.h>
#include <hip/hip_bf16.h>

#define B_ 4
#define S_ 4096
#define D_ 1024
#define H_ 128

typedef unsigned short u16;
typedef unsigned int u32;
typedef short s16x8 __attribute__((ext_vector_type(8)));   // 8 bf16 (4 VGPRs)
typedef float f32x4 __attribute__((ext_vector_type(4)));   // MFMA 16x16 acc
typedef float f32x16 __attribute__((ext_vector_type(16))); // MFMA 32x32 acc

__device__ __forceinline__ u16 f2bf(float f) {
    u32 x = __float_as_uint(f);
    u32 r = x + 0x7fffu + ((x >> 16) & 1u);   // RNE
    return (u16)(r >> 16);
}

// v_cvt_pk_bf16_f32: dst = {bf16(a) lo16, bf16(b) hi16}
__device__ __forceinline__ u32 cvtpk_bf16(float a, float b) {
    u32 r;
    asm("v_cvt_pk_bf16_f32 %0, %1, %2" : "=v"(r) : "v"(a), "v"(b));
    return r;
}
// v_permlane32_swap_b32: exchanges x.hi-lanes <-> y.lo-lanes (both updated)
__device__ __forceinline__ void pl32swap(u32& x, u32& y) {
    asm("v_permlane32_swap_b32 %0, %1" : "+v"(x), "+v"(y));
}

// async global->LDS, 16 B per lane (m97 pattern; zero staging VGPRs)
__device__ __forceinline__ void gl_lds16(const u16* g, u16* l) {
    __builtin_amdgcn_global_load_lds(
        (const __attribute__((address_space(1))) u32*)g,
        (__attribute__((address_space(3))) u32*)l, 16, 0, 0);
}

// ---------------------------------------------------------------------------
// Kernel 0: input dtype detection (fp32 vs bf16). Verified in round 3.
// ---------------------------------------------------------------------------
__global__ void detect_dtype_kernel(const u32* __restrict__ w, int* __restrict__ flag) {
    __shared__ int smax[256];
    const int tid = threadIdx.x;
    int m = 0;
    for (int i = tid; i < 1024; i += 256) {
        u32 x = w[i];
        m = max(m, max((int)((x >> 7) & 0xFF), (int)((x >> 23) & 0xFF)));
    }
    smax[tid] = m;
    __syncthreads();
    if (tid == 0) {
        int mm = 0;
        for (int i = 0; i < 256; ++i) mm = max(mm, smax[i]);
        *flag = (mm >= 200) ? 1 : 0;
    }
}

// ---------------------------------------------------------------------------
// Kernel 0b: W -> Wt, bf16, transposed + tiled so a B-fragment is 16 B
// contiguous: Wt[((mat*32+kt)*128 + n)*32 + k]. Tile (mat,kt) = 8 KB.
// ---------------------------------------------------------------------------
__global__ __launch_bounds__(256) void prep_w_kernel(
    const void* __restrict__ Wq, const void* __restrict__ Wk, const void* __restrict__ Wv,
    u16* __restrict__ Wt, const int* __restrict__ dflag)
{
    const int kt = blockIdx.x, mat = blockIdx.y;
    const void* W = (mat == 0) ? Wq : (mat == 1) ? Wk : Wv;
    const int isf = *dflag;
    const int t = threadIdx.x;
    const int kk = t >> 3;            // 0..31 (k within tile)
    const int n0 = (t & 7) * 16;      // 16 n per thread
    u16 vals[16];
    if (isf) {
        const float* wp = (const float*)W + (size_t)(kt * 32 + kk) * H_ + n0;
#pragma unroll
        for (int i = 0; i < 16; ++i) vals[i] = f2bf(wp[i]);
    } else {
        const u16* wp = (const u16*)W + (size_t)(kt * 32 + kk) * H_ + n0;
#pragma unroll
        for (int i = 0; i < 16; ++i) vals[i] = wp[i];
    }
    const size_t base = (size_t)(mat * 32 + kt) * 128;
#pragma unroll
    for (int i = 0; i < 16; ++i)
        Wt[(base + n0 + i) * 32 + kk] = vals[i];
}

// ---------------------------------------------------------------------------
// Kernel 1: fused QKV GEMM v4 (unchanged from measured-good round).
// ---------------------------------------------------------------------------
__global__ __launch_bounds__(256) void qkv_kernel(
    const void* __restrict__ Xv, const u16* __restrict__ Wt,
    u16* __restrict__ Qo, u16* __restrict__ Ko, u16* __restrict__ Vto,
    const int* __restrict__ dflag)
{
    __shared__ u16 Ws[2][384 * 32];                              // 2 x 24 KB
    __shared__ union { u16 qk[32 * 136]; u16 vt[128 * 40]; } OsU; // 10.2 KB

    const int isf = *dflag;
    const int tid = threadIdx.x;
    const int w = tid >> 6, lane = tid & 63;
    const int r = lane & 15, q = lane >> 4;
    const size_t m0 = (size_t)blockIdx.x * 32;

    f32x4 acc[2][6];   // [row strip][frag]
#pragma unroll
    for (int s2 = 0; s2 < 2; ++s2)
#pragma unroll
        for (int i = 0; i < 6; ++i) acc[s2][i] = (f32x4){0.f, 0.f, 0.f, 0.f};

    const float* xf0 = (const float*)Xv + (m0 + r) * D_;
    const float* xf1 = (const float*)Xv + (m0 + 16 + r) * D_;
    const u16*   xb0 = (const u16*)Xv + (m0 + r) * D_;
    const u16*   xb1 = (const u16*)Xv + (m0 + 16 + r) * D_;

    float4 af[2][2];   // fp32 A prefetch (2 strips x 8 floats)
    uint4  ab[2];      // bf16 A prefetch

    // ---- async-stage W tile kt=0 into Ws[0] ----
#pragma unroll
    for (int i = 0; i < 6; ++i) {
        int c = tid + i * 256;      // 1536 chunks of 16 B; mat = c>>9
        gl_lds16(Wt + (size_t)((c >> 9) * 32) * 4096 + (c & 511) * 8, &Ws[0][c * 8]);
    }
    // ---- A prefetch kt=0 ----
    if (isf) {
        af[0][0] = *(const float4*)(xf0 + q * 8);
        af[0][1] = *(const float4*)(xf0 + q * 8 + 4);
        af[1][0] = *(const float4*)(xf1 + q * 8);
        af[1][1] = *(const float4*)(xf1 + q * 8 + 4);
    } else {
        ab[0] = *(const uint4*)(xb0 + q * 8);
        ab[1] = *(const uint4*)(xb1 + q * 8);
    }

    for (int kt = 0; kt < 32; ++kt) {
        const int buf = kt & 1;
        __syncthreads();   // drains vmcnt: Ws[buf] + A(kt) ready; readers of Ws[buf^1] done

        if (kt + 1 < 32) {  // async-stage W tile kt+1 into the other buffer
#pragma unroll
            for (int i = 0; i < 6; ++i) {
                int c = tid + i * 256;
                gl_lds16(Wt + (size_t)((c >> 9) * 32 + kt + 1) * 4096 + (c & 511) * 8,
                         &Ws[buf ^ 1][c * 8]);
            }
        }

        // convert A regs (loaded last iteration) to bf16 frags
        s16x8 a[2];
        if (isf) {
#pragma unroll
            for (int s2 = 0; s2 < 2; ++s2) {
                union { u16 u[8]; s16x8 v; } pk;
                pk.u[0] = f2bf(af[s2][0].x); pk.u[1] = f2bf(af[s2][0].y);
                pk.u[2] = f2bf(af[s2][0].z); pk.u[3] = f2bf(af[s2][0].w);
                pk.u[4] = f2bf(af[s2][1].x); pk.u[5] = f2bf(af[s2][1].y);
                pk.u[6] = f2bf(af[s2][1].z); pk.u[7] = f2bf(af[s2][1].w);
                a[s2] = pk.v;
            }
        } else {
            a[0] = *(const s16x8*)&ab[0];
            a[1] = *(const s16x8*)&ab[1];
        }

        if (kt + 1 < 32) {   // A prefetch next kt (in flight during MFMAs)
            const int k0 = (kt + 1) * 32;
            if (isf) {
                af[0][0] = *(const float4*)(xf0 + k0 + q * 8);
                af[0][1] = *(const float4*)(xf0 + k0 + q * 8 + 4);
                af[1][0] = *(const float4*)(xf1 + k0 + q * 8);
                af[1][1] = *(const float4*)(xf1 + k0 + q * 8 + 4);
            } else {
                ab[0] = *(const uint4*)(xb0 + k0 + q * 8);
                ab[1] = *(const uint4*)(xb1 + k0 + q * 8);
            }
        }

#pragma unroll
        for (int i = 0; i < 6; ++i) {
            int c = w * 6 + i;   // mat = c>>3, nt = c&7
            s16x8 b = *(const s16x8*)&Ws[buf][(c >> 3) * 4096 + ((c & 7) * 16 + r) * 32 + q * 8];
            acc[0][i] = __builtin_amdgcn_mfma_f32_16x16x32_bf16(a[0], b, acc[0][i], 0, 0, 0);
            acc[1][i] = __builtin_amdgcn_mfma_f32_16x16x32_bf16(a[1], b, acc[1][i], 0, 0, 0);
        }
    }

    // ---- epilogue: Q and K row-major via LDS bounce ----
    u16* outs[2] = {Qo, Ko};
    for (int m = 0; m < 2; ++m) {
        const float sc = (m == 0) ? 0.08838834764831845f : 1.0f;
        __syncthreads();
#pragma unroll
        for (int i = 0; i < 6; ++i) {
            int c = w * 6 + i;
            if ((c >> 3) == m) {
                int nt = c & 7;
#pragma unroll
                for (int s2 = 0; s2 < 2; ++s2)
#pragma unroll
                    for (int reg = 0; reg < 4; ++reg)
                        OsU.qk[(s2 * 16 + q * 4 + reg) * 136 + nt * 16 + r] = f2bf(acc[s2][i][reg] * sc);
            }
        }
        __syncthreads();
        u16* Out = outs[m];
#pragma unroll
        for (int it = 0; it < 2; ++it) {
            int c = tid + it * 256;
            int row = c >> 4, col = (c & 15) * 8;
            *(uint4*)(Out + (m0 + row) * H_ + col) = *(const uint4*)&OsU.qk[row * 136 + col];
        }
    }

    // ---- V transposed: OsU.vt[h][s_local], then Vt[b][h][s] global ----
    __syncthreads();
#pragma unroll
    for (int i = 0; i < 6; ++i) {
        int c = w * 6 + i;
        if ((c >> 3) == 2) {
            int nt = c & 7;
#pragma unroll
            for (int s2 = 0; s2 < 2; ++s2)
#pragma unroll
                for (int reg = 0; reg < 4; ++reg)
                    OsU.vt[(nt * 16 + r) * 40 + s2 * 16 + q * 4 + reg] = f2bf(acc[s2][i][reg]);
        }
    }
    __syncthreads();
    {
        const int bb = blockIdx.x >> 7;           // 128 blocks per batch
        const int s0 = (blockIdx.x & 127) * 32;
        // 128 h-rows x 32 s = 512 uint4 chunks: h = c>>2, sh = (c&3)*8
#pragma unroll
        for (int it = 0; it < 2; ++it) {
            int c = tid + it * 256;
            int h = c >> 2, sh = (c & 3) * 8;
            *(uint4*)(Vto + ((size_t)bb * H_ + h) * S_ + s0 + sh) =
                *(const uint4*)&OsU.vt[h * 40 + sh];
        }
    }
}

// ---------------------------------------------------------------------------
// Kernel 2: causal flash attention — swapped-QK^T in-register softmax,
// 8 WAVES (512 threads), 8-way key split. Round-6 post-mortem: the clean
// barrier-free k-loop still pays ~1320 cy/chunk vs ~500 of chain work
// because LDS 66KB/256-thread block capped residency at ~1.2 waves/SIMD --
// nothing to run during L2 load waits. This version keeps the k-loop body
// BYTE-IDENTICAL and lifts occupancy to 4 waves/SIMD: 512-thread blocks
// (2 blocks/CU, 16 waves/CU), keys split c = w, w+8, ...; epilogue combine
// in two phases (waves 0-3 write opS[4][32][128], barrier, waves 4-7 add)
// + parallel normalize/store. Pairing grid: bid and bid+256 (qt, 127-qt)
// land on the same CU slot under round-robin dispatch -> constant work/CU.
// ---------------------------------------------------------------------------
__global__ __launch_bounds__(512) void attn_kernel(
    const u16* __restrict__ Q, const u16* __restrict__ K, const u16* __restrict__ Vt,
    void* __restrict__ out, const int* __restrict__ dflag)
{
    __shared__ float opS[4][32][128];   // combine buffers (64 KB)
    __shared__ float lpS[8][32];        // per-wave l partials

    const int isf = *dflag;
    const int tid = threadIdx.x;
    const int w = tid >> 6, lane = tid & 63;
    const int l31 = lane & 31, hi = lane >> 5;
    const int bid = blockIdx.x;
    const int b = bid & 3;
    const int qt = (bid < 256) ? (bid >> 2) : (127 - ((bid - 256) >> 2));

    const u16* Qg  = Q  + ((size_t)b * S_ + (size_t)qt * 32) * H_;
    const u16* Kg  = K  + (size_t)b * S_ * H_;
    const u16* Vtg = Vt + (size_t)b * H_ * S_;

    // Q as B-operand frags: lane -> qrow = l31, k(h) = sl*16 + hi*8 + [0..8)
    s16x8 qf[8];
#pragma unroll
    for (int sl = 0; sl < 8; ++sl)
        qf[sl] = *(const s16x8*)(Qg + (size_t)l31 * H_ + sl * 16 + hi * 8);

    f32x16 accO[4];
#pragma unroll
    for (int hg = 0; hg < 4; ++hg)
#pragma unroll
        for (int i = 0; i < 16; ++i) accO[hg][i] = 0.f;
    float lp = 0.f;

    // K as A-operand frags for first chunk: lane -> key = l31, k(h) likewise
    s16x8 kf[8];
    if (w <= qt) {
#pragma unroll
        for (int sl = 0; sl < 8; ++sl)
            kf[sl] = *(const s16x8*)(Kg + ((size_t)w * 32 + l31) * H_ + sl * 16 + hi * 8);
    }

    for (int c = w; c <= qt; c += 8) {
        const int kb = c * 32;

        // V as B-operand frags: lane -> h = hg*32+l31, k(key) = ks*16 + hi*8 + [0..8)
        s16x8 vf[4][2];
#pragma unroll
        for (int hg = 0; hg < 4; ++hg)
#pragma unroll
            for (int ks = 0; ks < 2; ++ks)
                vf[hg][ks] = *(const s16x8*)(Vtg + (size_t)(hg * 32 + l31) * S_ + kb + ks * 16 + hi * 8);

        // ---- S^T = K Q^T : lane holds qrow = l31, key(r,hi) = (r&3)+8*(r>>2)+4*hi ----
        f32x16 sacc;
#pragma unroll
        for (int i = 0; i < 16; ++i) sacc[i] = 0.f;
#pragma unroll
        for (int sl = 0; sl < 8; ++sl)
            sacc = __builtin_amdgcn_mfma_f32_32x32x16_bf16(kf[sl], qf[sl], sacc, 0, 0, 0);

        // ---- prefetch K frags for this wave's next chunk (covered by softmax+PV) ----
        if (c + 8 <= qt) {
#pragma unroll
            for (int sl = 0; sl < 8; ++sl)
                kf[sl] = *(const s16x8*)(Kg + ((size_t)(kb + 256) + l31) * H_ + sl * 16 + hi * 8);
        }

        // ---- lane-local softmax (no max-pass; clamp 80), mask own diagonal chunk ----
        const bool diag = (c == qt);
        float p[16];
#pragma unroll
        for (int r = 0; r < 16; ++r) {
            float s = fminf(sacc[r], 80.f);
            float pv = __expf(s);
            if (diag && ((r & 3) + 8 * (r >> 2) + 4 * hi) > l31) pv = 0.f;
            lp += pv;
            p[r] = pv;
        }

        // ---- P -> PV A-frags: 8 cvt_pk + 4 permlane32_swap (T12 recipe) ----
        u32 w01 = cvtpk_bf16(p[0], p[1]),  w23 = cvtpk_bf16(p[2], p[3]);
        u32 w45 = cvtpk_bf16(p[4], p[5]),  w67 = cvtpk_bf16(p[6], p[7]);
        pl32swap(w01, w45);
        pl32swap(w23, w67);
        u32 x01 = cvtpk_bf16(p[8], p[9]),  x23 = cvtpk_bf16(p[10], p[11]);
        u32 x45 = cvtpk_bf16(p[12], p[13]), x67 = cvtpk_bf16(p[14], p[15]);
        pl32swap(x01, x45);
        pl32swap(x23, x67);
        union { u32 u[4]; s16x8 v; } pa0, pa1;
        pa0.u[0] = w01; pa0.u[1] = w23; pa0.u[2] = w45; pa0.u[3] = w67;
        pa1.u[0] = x01; pa1.u[1] = x23; pa1.u[2] = x45; pa1.u[3] = x67;

        // ---- O += P V : D lane holds h = hg*32+l31, qrow(r,hi) ----
#pragma unroll
        for (int hg = 0; hg < 4; ++hg) {
            accO[hg] = __builtin_amdgcn_mfma_f32_32x32x16_bf16(pa0.v, vf[hg][0], accO[hg], 0, 0, 0);
            accO[hg] = __builtin_amdgcn_mfma_f32_32x32x16_bf16(pa1.v, vf[hg][1], accO[hg], 0, 0, 0);
        }
    }

    // ---- combine the two key-halves of l (lane pair L, L+32) ----
    lp += __shfl_xor(lp, 32);
    if (lane < 32) lpS[w][l31] = lp;

    // ---- two-phase combine: waves 0-3 write, waves 4-7 accumulate ----
    if (w < 4) {
#pragma unroll
        for (int hg = 0; hg < 4; ++hg)
#pragma unroll
            for (int r = 0; r < 16; ++r)
                opS[w][(r & 3) + 8 * (r >> 2) + 4 * hi][hg * 32 + l31] = accO[hg][r];
    }
    __syncthreads();
    if (w >= 4) {
#pragma unroll
        for (int hg = 0; hg < 4; ++hg)
#pragma unroll
            for (int r = 0; r < 16; ++r)
                opS[w - 4][(r & 3) + 8 * (r >> 2) + 4 * hi][hg * 32 + l31] += accO[hg][r];
    }
    __syncthreads();

    // ---- final: sum 4 buffers, normalize, store (512 threads) ----
    {
        const int qrow = tid >> 4;           // 0..31
        const int hs = (tid & 15) * 8;       // 0..120
        float l = 0.f;
#pragma unroll
        for (int s = 0; s < 8; ++s) l += lpS[s][qrow];
        const float inv = 1.0f / l;
        float vals[8];
#pragma unroll
        for (int i = 0; i < 8; i += 4) {
            float4 a0 = *(const float4*)&opS[0][qrow][hs + i];
            float4 a1 = *(const float4*)&opS[1][qrow][hs + i];
            float4 a2 = *(const float4*)&opS[2][qrow][hs + i];
            float4 a3 = *(const float4*)&opS[3][qrow][hs + i];
            vals[i + 0] = (a0.x + a1.x + a2.x + a3.x) * inv;
            vals[i + 1] = (a0.y + a1.y + a2.y + a3.y) * inv;
            vals[i + 2] = (a0.z + a1.z + a2.z + a3.z) * inv;
            vals[i + 3] = (a0.w + a1.w + a2.w + a3.w) * inv;
        }
        const size_t orow = (size_t)b * S_ + (size_t)qt * 32 + qrow;
        if (isf) {
            float* dst = (float*)out + orow * H_ + hs;
            *(float4*)(dst) = *(const float4*)(&vals[0]);
            *(float4*)(dst + 4) = *(const float4*)(&vals[4]);
        } else {
            u16* dst = (u16*)out + orow * H_ + hs;
            union { u16 u[8]; uint4 v; } pk;
#pragma unroll
            for (int i = 0; i < 8; ++i) pk.u[i] = f2bf(vals[i]);
            *(uint4*)dst = pk.v;
        }
    }
}

extern "C" void kernel_launch(void* const* d_in, const int* in_sizes, int n_in,
                              void* d_out, int out_size, void* d_ws, size_t ws_size,
                              hipStream_t stream) {
    (void)in_sizes; (void)n_in; (void)out_size; (void)ws_size;
    const void* X  = d_in[0];
    const void* Wq = d_in[1];
    const void* Wk = d_in[2];
    const void* Wv = d_in[3];

    int* dflag = (int*)d_ws;                          // 256 B header
    u16* Qw = (u16*)((char*)d_ws + 256);
    const size_t n = (size_t)B_ * S_ * H_;            // 2M elems per tensor
    u16* Kw = Qw + n;
    u16* Vtw = Kw + n;                                // V stored transposed [b][h][s]
    u16* Wt = Vtw + n;                                // 3*1024*128 bf16 = 768 KB

    detect_dtype_kernel<<<1, 256, 0, stream>>>((const u32*)Wq, dflag);
    prep_w_kernel<<<dim3(32, 3), 256, 0, stream>>>(Wq, Wk, Wv, Wt, dflag);
    qkv_kernel<<<512, 256, 0, stream>>>(X, Wt, Qw, Kw, Vtw, dflag);
    attn_kernel<<<512, 512, 0, stream>>>(Qw, Kw, Vtw, d_out, dflag);
}